// Round 9
// baseline (114.860 us; speedup 1.0000x reference)
//
#include <hip/hip_runtime.h>
#include <cfloat>
#include <cstddef>

#define NBATCH 2
#define NPTS   5000
#define NF     64
#define NB     10      // bins = N / BIN_SIZE
#define BINSZ  500
#define TOPK   5
#define ROTCOLS 100    // MAX_NUM_BINS/2 columns in rotations

#define NCB    8                       // col-blocks per group
#define CBS    64                      // cols per col-block (last = 52)
#define NCAND  (NCB * TOPK)            // 40 candidates per row
#define ROW4   (NPTS / 4)              // 1250 float4 per output row
#define OUT4   (NBATCH * NPTS * NPTS / 4)   // 12.5M float4 in d_out

// zero-work split (float4 units): rows [0,1000) in K1, [1000,1800) in K2,
// [1800,7800) in K3, [7800,10000) zeroed+injected by K4 blocks themselves.
#define Z1_BEG 0
#define Z1_END (1000 * ROW4)           // 1,250,000
#define Z2_END (1800 * ROW4)           // 2,250,000
#define Z3_END (7800 * ROW4)           // 9,750,000
#define NZ1    400
#define NZ2    300
#define NZ3    1800
#define ROWCUT 7800                    // first row K4 zeroes itself

typedef float nfloat4 __attribute__((ext_vector_type(4)));   // native vec for NT stores

__device__ __forceinline__ void nt_zero4(float4* p) {
    nfloat4 z = {0.f, 0.f, 0.f, 0.f};
    __builtin_nontemporal_store(z, (nfloat4*)p);
}

__device__ __forceinline__ void zero_range(float4* o4, size_t beg, size_t end,
                                           int nblk, int zid, int tid) {
    const size_t total = end - beg;
    const size_t chunk = (total + nblk - 1) / nblk;
    size_t lo = beg + (size_t)zid * chunk;
    size_t hi = lo + chunk; if (hi > end) hi = end;
    for (size_t i = lo + tid; i < hi; i += 256) nt_zero4(o4 + i);
}

// ---------------------------------------------------------------------------
// K1: blocks [0,2500) = per-point LSH bin + squared norm (1 wave/point);
//     blocks [2500,2900) = zero-stream rows [0,1000).
// ---------------------------------------------------------------------------
__global__ __launch_bounds__(256) void bin_norm_zero_k(const float* __restrict__ pts,
                                                       const float* __restrict__ rot,
                                                       int* __restrict__ bin_idx,
                                                       float* __restrict__ na,
                                                       float* __restrict__ out) {
    const int t = threadIdx.x;
    if (blockIdx.x >= 2500) {
        zero_range((float4*)out, Z1_BEG, Z1_END, NZ1, blockIdx.x - 2500, t);
        return;
    }
    __shared__ float srot[NF * 5];
    for (int i = t; i < NF * 5; i += 256) {      // full 320-element fill
        int f = i / 5, h = i - 5 * f;
        srot[i] = rot[f * ROTCOLS + h];
    }
    __syncthreads();

    int pt   = blockIdx.x * 4 + (t >> 6);
    int lane = t & 63;
    float p  = pts[(size_t)pt * NF + lane];
    float nn = p * p;
    float c0 = p * srot[lane * 5 + 0];
    float c1 = p * srot[lane * 5 + 1];
    float c2 = p * srot[lane * 5 + 2];
    float c3 = p * srot[lane * 5 + 3];
    float c4 = p * srot[lane * 5 + 4];
    #pragma unroll
    for (int off = 32; off > 0; off >>= 1) {
        nn += __shfl_xor(nn, off);
        c0 += __shfl_xor(c0, off);
        c1 += __shfl_xor(c1, off);
        c2 += __shfl_xor(c2, off);
        c3 += __shfl_xor(c3, off);
        c4 += __shfl_xor(c4, off);
    }
    if (lane == 0) {
        float c[5] = {c0, c1, c2, c3, c4};
        float bv = c[0]; int bi = 0;
        #pragma unroll
        for (int h = 1; h < 5; ++h) if (c[h] > bv) { bv = c[h]; bi = h; }
        #pragma unroll
        for (int h = 0; h < 5; ++h) if (-c[h] > bv) { bv = -c[h]; bi = h + 5; }
        bin_idx[pt] = bi;   // first-max wins, matches jnp.argmax
        na[pt] = nn;
    }
}

// ---------------------------------------------------------------------------
// K2: blocks [0,2) = stable counting sort (also emits inverse permutation);
//     blocks [2,302) = zero-stream rows [1000,1800).
// ---------------------------------------------------------------------------
__global__ __launch_bounds__(256) void sort_zero_k(const int* __restrict__ bin_idx,
                                                   int* __restrict__ order,
                                                   int* __restrict__ inv,
                                                   float* __restrict__ out) {
    const int t = threadIdx.x;
    if (blockIdx.x >= NBATCH) {
        zero_range((float4*)out, Z1_END, Z2_END, NZ2, blockIdx.x - NBATCH, t);
        return;
    }
    const int b = blockIdx.x;
    const int w = t >> 6, lane = t & 63;
    __shared__ int sh_bin[NPTS];
    __shared__ int sh_hist[256][NB];
    __shared__ int sh_part[NB][16];
    __shared__ int sh_tot[NB + 1];

    for (int i = t; i < NPTS; i += 256) sh_bin[i] = bin_idx[b * NPTS + i];
    #pragma unroll
    for (int h = 0; h < NB; ++h) sh_hist[t][h] = 0;
    __syncthreads();

    const int CH = (NPTS + 255) / 256;            // 20
    const int i0 = t * CH;
    const int i1 = (i0 + CH < NPTS) ? (i0 + CH) : NPTS;
    for (int i = i0; i < i1; ++i) sh_hist[t][sh_bin[i]]++;
    __syncthreads();

    if (t < NB * 16) {
        int h = t >> 4, s = t & 15;
        int sum = 0;
        #pragma unroll
        for (int k = 0; k < 16; ++k) sum += sh_hist[s * 16 + k][h];
        sh_part[h][s] = sum;
    }
    __syncthreads();
    if (t < NB) {
        int tot = 0;
        #pragma unroll
        for (int s = 0; s < 16; ++s) tot += sh_part[t][s];
        sh_tot[t + 1] = tot;
    }
    __syncthreads();
    if (t == 0) {
        sh_tot[0] = 0;
        for (int h = 1; h <= NB; ++h) sh_tot[h] += sh_tot[h - 1];
    }
    __syncthreads();

    for (int h = w; h < NB; h += 4) {
        int base = lane * 4;
        int v0 = sh_hist[base + 0][h];
        int v1 = sh_hist[base + 1][h];
        int v2 = sh_hist[base + 2][h];
        int v3 = sh_hist[base + 3][h];
        int lt = v0 + v1 + v2 + v3;
        int x = lt;
        #pragma unroll
        for (int off = 1; off < 64; off <<= 1) {
            int y = __shfl_up(x, off);
            if (lane >= off) x += y;
        }
        int excl = x - lt + sh_tot[h];
        sh_hist[base + 0][h] = excl;
        sh_hist[base + 1][h] = excl + v0;
        sh_hist[base + 2][h] = excl + v0 + v1;
        sh_hist[base + 3][h] = excl + v0 + v1 + v2;
    }
    __syncthreads();

    for (int i = i0; i < i1; ++i) {
        int h = sh_bin[i];
        int sp = sh_hist[t][h]++;
        order[b * NPTS + sp] = i;
        inv[b * NPTS + i] = sp;               // inverse permutation for K4
    }
}

// ---------------------------------------------------------------------------
// K3: blocks [0,160) = pairwise d^2 + per-colblock top-5 (round-5-validated:
//     (group, 64-col slice) per block, cols in 16KB LDS, 2 rows/lane);
//     blocks [160,1960) = zero-stream rows [1800,7800).
// ---------------------------------------------------------------------------
__global__ __launch_bounds__(256) void pair_zero_k(const float* __restrict__ pts,
                                                   const float* __restrict__ na,
                                                   const int* __restrict__ order,
                                                   float* __restrict__ wv,
                                                   int* __restrict__ wd,
                                                   float* __restrict__ out) {
    const int bx  = blockIdx.x;
    const int tid = threadIdx.x;

    if (bx >= NBATCH * NB * NCB) {           // ---- zero-stream path ----
        zero_range((float4*)out, Z2_END, Z3_END, NZ3, bx - NBATCH * NB * NCB, tid);
        return;
    }

    // ---- compute path (verbatim round-5 structure) ----
    const int g   = bx / NCB;
    const int cb  = bx - g * NCB;
    const int b   = g / NB;
    const int grp = g - b * NB;
    const int c0  = cb * CBS;
    const int ncols = (c0 + CBS <= BINSZ) ? CBS : (BINSZ - c0);   // 64 or 52

    __shared__ float sh_cols[CBS * NF];      // 16 KB
    __shared__ float sh_cna[CBS];

    const int* ord = order + b * NPTS + grp * BINSZ;
    const float4* p4 = (const float4*)(pts + (size_t)b * NPTS * NF);
    float4* sc4 = (float4*)sh_cols;

    for (int i = tid; i < ncols * 16; i += 256) {
        int c = i >> 4, q = i & 15;
        sc4[c * 16 + q] = p4[(size_t)ord[c0 + c] * 16 + q];
    }
    if (tid < ncols) sh_cna[tid] = na[b * NPTS + ord[c0 + tid]];
    __syncthreads();

    const int p0 = tid, p1 = tid + 256;
    const bool h1 = (p1 < BINSZ);            // threads 0..243 own a 2nd row
    const int gi0 = ord[p0];
    const int gi1 = h1 ? ord[p1] : gi0;
    float4 r0[16], r1[16];
    #pragma unroll
    for (int q = 0; q < 16; ++q) {
        r0[q] = p4[(size_t)gi0 * 16 + q];
        r1[q] = p4[(size_t)gi1 * 16 + q];
    }
    const float na0 = na[b * NPTS + gi0];
    const float na1 = na[b * NPTS + gi1];

    float tv0[TOPK], tv1[TOPK]; int tp0[TOPK], tp1[TOPK];
    #pragma unroll
    for (int s = 0; s < TOPK; ++s) { tv0[s] = FLT_MAX; tv1[s] = FLT_MAX; tp0[s] = 0; tp1[s] = 0; }

    for (int c = 0; c < ncols; ++c) {
        const float4* cq = sc4 + c * 16;     // wave-uniform broadcast reads
        float a0 = 0.f, a1 = 0.f;
        #pragma unroll
        for (int q = 0; q < 16; ++q) {       // identical accumulation order everywhere
            float4 cc = cq[q];
            a0 += r0[q].x * cc.x; a0 += r0[q].y * cc.y;
            a0 += r0[q].z * cc.z; a0 += r0[q].w * cc.w;
            a1 += r1[q].x * cc.x; a1 += r1[q].y * cc.y;
            a1 += r1[q].z * cc.z; a1 += r1[q].w * cc.w;
        }
        const float cna = sh_cna[c];
        const int pos = c0 + c;
        float d0 = na0 - 2.f * a0 + cna;
        float d1 = na1 - 2.f * a1 + cna;
        if (d0 < tv0[TOPK - 1]) {            // strict <: ties keep earlier pos
            tv0[TOPK - 1] = d0; tp0[TOPK - 1] = pos;
            #pragma unroll
            for (int s = TOPK - 1; s > 0; --s) {
                if (tv0[s] < tv0[s - 1]) {
                    float fv = tv0[s]; tv0[s] = tv0[s - 1]; tv0[s - 1] = fv;
                    int   fi = tp0[s]; tp0[s] = tp0[s - 1]; tp0[s - 1] = fi;
                }
            }
        }
        if (h1 && d1 < tv1[TOPK - 1]) {
            tv1[TOPK - 1] = d1; tp1[TOPK - 1] = pos;
            #pragma unroll
            for (int s = TOPK - 1; s > 0; --s) {
                if (tv1[s] < tv1[s - 1]) {
                    float fv = tv1[s]; tv1[s] = tv1[s - 1]; tv1[s - 1] = fv;
                    int   fi = tp1[s]; tp1[s] = tp1[s - 1]; tp1[s - 1] = fi;
                }
            }
        }
    }

    const int slotbase = (b * NB + grp) * BINSZ;
    {
        size_t wbase = ((size_t)(slotbase + p0) * NCB + cb) * TOPK;
        #pragma unroll
        for (int s = 0; s < TOPK; ++s) { wv[wbase + s] = tv0[s]; wd[wbase + s] = tp0[s]; }
    }
    if (h1) {
        size_t wbase = ((size_t)(slotbase + p1) * NCB + cb) * TOPK;
        #pragma unroll
        for (int s = 0; s < TOPK; ++s) { wv[wbase + s] = tv1[s]; wd[wbase + s] = tp1[s]; }
    }
}

// ---------------------------------------------------------------------------
// K4: 2500 blocks x 4 output rows. Blocks with rows >= ROWCUT zero their own
// rows first (tail of the zero split); then threads 0..3 merge the 8 partial
// top-5 lists for their row by exact (d2,pos) lexicographic order (bitwise ==
// round-5-validated merge) and inject the 5 exp values.
// ---------------------------------------------------------------------------
__global__ __launch_bounds__(256) void merge_inject_k(const float* __restrict__ wv,
                                                      const int* __restrict__ wd,
                                                      const int* __restrict__ order,
                                                      const int* __restrict__ inv,
                                                      float* __restrict__ out) {
    const int t = threadIdx.x;
    const size_t gr0 = (size_t)blockIdx.x * 4;           // first of 4 global rows
    if (gr0 >= ROWCUT) {                                 // zero own rows
        float4* o4 = ((float4*)out) + gr0 * ROW4;
        const float4 z4 = make_float4(0.f, 0.f, 0.f, 0.f);
        for (int i = t; i < 4 * ROW4; i += 256) o4[i] = z4;
        __syncthreads();                                 // drain before inject
    }
    if (t < 4) {
        const size_t g = gr0 + t;                        // global row = b*NPTS+src
        const int b  = (int)(g / NPTS);
        const int sp = inv[g];                           // slot within batch
        const int grp = sp / BINSZ;

        float cv[NCAND]; int cp[NCAND];
        const size_t base = ((size_t)b * NPTS + sp) * NCAND;
        #pragma unroll
        for (int k = 0; k < NCAND; ++k) { cv[k] = wv[base + k]; cp[k] = wd[base + k]; }

        const int* ord = order + b * NPTS + grp * BINSZ;
        unsigned long long used = 0;
        float* orow = out + g * NPTS;
        #pragma unroll
        for (int s = 0; s < TOPK; ++s) {
            float bv = FLT_MAX; int bp = 0x7fffffff; int bk = 0;
            #pragma unroll
            for (int k = 0; k < NCAND; ++k) {
                bool ok = !((used >> k) & 1ull);
                bool better = ok && ((cv[k] < bv) || (cv[k] == bv && cp[k] < bp));
                if (better) { bv = cv[k]; bp = cp[k]; bk = k; }
            }
            used |= (1ull << bk);
            float val = expf(-0.1f * sqrtf(fmaxf(bv, 1e-6f)));
            orow[ord[bp]] = val;
        }
    }
}

// ---------------------------------------------------------------------------
extern "C" void kernel_launch(void* const* d_in, const int* in_sizes, int n_in,
                              void* d_out, int out_size, void* d_ws, size_t ws_size,
                              hipStream_t stream) {
    const float* points = (const float*)d_in[0];
    const float* rot    = (const float*)d_in[1];
    float* out = (float*)d_out;

    char* ws = (char*)d_ws;
    int*   bin_idx = (int*)ws;   ws += NBATCH * NPTS * sizeof(int);
    float* na      = (float*)ws; ws += NBATCH * NPTS * sizeof(float);
    int*   order   = (int*)ws;   ws += NBATCH * NPTS * sizeof(int);
    int*   inv     = (int*)ws;   ws += NBATCH * NPTS * sizeof(int);
    float* wv      = (float*)ws; ws += (size_t)NBATCH * NPTS * NCAND * sizeof(float);
    int*   wd      = (int*)ws;   // total ws use ~3.4 MB

    bin_norm_zero_k<<<2500 + NZ1, 256, 0, stream>>>(points, rot, bin_idx, na, out);
    sort_zero_k<<<NBATCH + NZ2, 256, 0, stream>>>(bin_idx, order, inv, out);
    pair_zero_k<<<NBATCH * NB * NCB + NZ3, 256, 0, stream>>>(points, na, order, wv, wd, out);
    merge_inject_k<<<(NBATCH * NPTS) / 4, 256, 0, stream>>>(wv, wd, order, inv, out);
}

// Round 10
// 104.376 us; speedup vs baseline: 1.1004x; 1.1004x over previous
//
#include <hip/hip_runtime.h>
#include <cfloat>
#include <cstddef>

#define NBATCH 2
#define NPTS   5000
#define NF     64
#define NB     10      // bins = N / BIN_SIZE
#define BINSZ  500
#define TOPK   5
#define ROTCOLS 100    // MAX_NUM_BINS/2 columns in rotations

#define NZ     3500                         // zero-ballast blocks in K1
#define OUT4   (NBATCH * NPTS * NPTS / 4)   // 12.5M float4 in d_out
#define CPW    63                           // cols per wave (8 waves x 63 >= 500)

// ---------------------------------------------------------------------------
// K1: blocks [0,2500) = per-point LSH bin + squared norm (1 wave/point,
//     validated verbatim); blocks [2500,2500+NZ) = zero d_out (plain stores,
//     R5-style — NT stores regressed in R9).
// ---------------------------------------------------------------------------
__global__ __launch_bounds__(256) void bin_norm_zero_k(const float* __restrict__ pts,
                                                       const float* __restrict__ rot,
                                                       int* __restrict__ bin_idx,
                                                       float* __restrict__ na,
                                                       float* __restrict__ out) {
    const int t = threadIdx.x;
    if (blockIdx.x >= 2500) {                // ---- zero-stream path ----
        const int z = blockIdx.x - 2500;
        const int chunk = (OUT4 + NZ - 1) / NZ;            // 3572
        const size_t base = (size_t)z * chunk;
        size_t end = base + chunk; if (end > (size_t)OUT4) end = OUT4;
        float4* o4 = (float4*)out;
        const float4 z4 = make_float4(0.f, 0.f, 0.f, 0.f);
        for (size_t i = base + t; i < end; i += 256) o4[i] = z4;
        return;
    }
    __shared__ float srot[NF * 5];
    for (int i = t; i < NF * 5; i += 256) {  // full 320-element fill
        int f = i / 5, h = i - 5 * f;
        srot[i] = rot[f * ROTCOLS + h];
    }
    __syncthreads();

    int pt   = blockIdx.x * 4 + (t >> 6);
    int lane = t & 63;
    float p  = pts[(size_t)pt * NF + lane];
    float nn = p * p;
    float c0 = p * srot[lane * 5 + 0];
    float c1 = p * srot[lane * 5 + 1];
    float c2 = p * srot[lane * 5 + 2];
    float c3 = p * srot[lane * 5 + 3];
    float c4 = p * srot[lane * 5 + 4];
    #pragma unroll
    for (int off = 32; off > 0; off >>= 1) {
        nn += __shfl_xor(nn, off);
        c0 += __shfl_xor(c0, off);
        c1 += __shfl_xor(c1, off);
        c2 += __shfl_xor(c2, off);
        c3 += __shfl_xor(c3, off);
        c4 += __shfl_xor(c4, off);
    }
    if (lane == 0) {
        float c[5] = {c0, c1, c2, c3, c4};
        float bv = c[0]; int bi = 0;
        #pragma unroll
        for (int h = 1; h < 5; ++h) if (c[h] > bv) { bv = c[h]; bi = h; }
        #pragma unroll
        for (int h = 0; h < 5; ++h) if (-c[h] > bv) { bv = -c[h]; bi = h + 5; }
        bin_idx[pt] = bi;   // first-max wins, matches jnp.argmax
        na[pt] = nn;
    }
}

// ---------------------------------------------------------------------------
// K2: stable counting sort, fully parallelized phases (validated verbatim).
// ---------------------------------------------------------------------------
__global__ __launch_bounds__(256) void sort_k(const int* __restrict__ bin_idx,
                                              int* __restrict__ order) {
    const int b = blockIdx.x;
    const int t = threadIdx.x;
    const int w = t >> 6, lane = t & 63;
    __shared__ int sh_bin[NPTS];
    __shared__ int sh_hist[256][NB];
    __shared__ int sh_part[NB][16];
    __shared__ int sh_tot[NB + 1];

    for (int i = t; i < NPTS; i += 256) sh_bin[i] = bin_idx[b * NPTS + i];
    #pragma unroll
    for (int h = 0; h < NB; ++h) sh_hist[t][h] = 0;
    __syncthreads();

    const int CH = (NPTS + 255) / 256;            // 20
    const int i0 = t * CH;
    const int i1 = (i0 + CH < NPTS) ? (i0 + CH) : NPTS;
    for (int i = i0; i < i1; ++i) sh_hist[t][sh_bin[i]]++;
    __syncthreads();

    if (t < NB * 16) {
        int h = t >> 4, s = t & 15;
        int sum = 0;
        #pragma unroll
        for (int k = 0; k < 16; ++k) sum += sh_hist[s * 16 + k][h];
        sh_part[h][s] = sum;
    }
    __syncthreads();
    if (t < NB) {
        int tot = 0;
        #pragma unroll
        for (int s = 0; s < 16; ++s) tot += sh_part[t][s];
        sh_tot[t + 1] = tot;
    }
    __syncthreads();
    if (t == 0) {
        sh_tot[0] = 0;
        for (int h = 1; h <= NB; ++h) sh_tot[h] += sh_tot[h - 1];
    }
    __syncthreads();

    for (int h = w; h < NB; h += 4) {
        int base = lane * 4;
        int v0 = sh_hist[base + 0][h];
        int v1 = sh_hist[base + 1][h];
        int v2 = sh_hist[base + 2][h];
        int v3 = sh_hist[base + 3][h];
        int lt = v0 + v1 + v2 + v3;
        int x = lt;
        #pragma unroll
        for (int off = 1; off < 64; off <<= 1) {
            int y = __shfl_up(x, off);
            if (lane >= off) x += y;
        }
        int excl = x - lt + sh_tot[h];
        sh_hist[base + 0][h] = excl;
        sh_hist[base + 1][h] = excl + v0;
        sh_hist[base + 2][h] = excl + v0 + v1;
        sh_hist[base + 3][h] = excl + v0 + v1 + v2;
    }
    __syncthreads();

    for (int i = i0; i < i1; ++i) {
        int h = sh_bin[i];
        order[b * NPTS + sh_hist[t][h]++] = i;
    }
}

// ---------------------------------------------------------------------------
// K3: readlane-gram + in-block 8-way merge + inject. Grid: 20 groups x 8
// row-blocks = 160 blocks of 512 threads (8 waves).
// Lane owns row rb*64+lane (64 floats in VGPRs). Wave w owns cols
// [w*63, min(w*63+63,500)). Per col: one coalesced 256B load (lane k holds
// col[k]), then 64 unrolled {readlane -> SGPR, v_fmac} steps — NO LDS on the
// critical path, pure VALU. Accumulation order k=0..63 == validated xyzw/q
// order. Per-wave top-5 (strict <, pos ascending) -> LDS -> 8-way
// lexicographic merge (low wave = earlier cols wins ties) == single-scan
// selection (validated in rounds 1-5). exp for 5 winners, inject into the
// K1-zeroed output.
// ---------------------------------------------------------------------------
__global__ __launch_bounds__(512) void pair_merge_inject_k(const float* __restrict__ pts,
                                                           const float* __restrict__ na,
                                                           const int* __restrict__ order,
                                                           float* __restrict__ out) {
    const int bx   = blockIdx.x;
    const int g    = bx >> 3;        // 0..19
    const int rb   = bx & 7;         // row-block 0..7
    const int b    = g / NB;
    const int grp  = g - b * NB;
    const int tid  = threadIdx.x;
    const int w    = tid >> 6;       // wave 0..7 (col partition)
    const int lane = tid & 63;

    __shared__ float sh_mv[8][64][TOPK];
    __shared__ int   sh_mi[8][64][TOPK];

    const int* ord = order + b * NPTS + grp * BINSZ;
    const float*  pb  = pts + (size_t)b * NPTS * NF;
    const float4* p4  = (const float4*)pb;
    const float*  nab = na + b * NPTS;

    const int prow = rb * 64 + lane;
    const int pcl  = (prow < BINSZ) ? prow : (BINSZ - 1);  // clamp; never written
    const int gi   = ord[pcl];
    float4 r[16];
    #pragma unroll
    for (int q = 0; q < 16; ++q) r[q] = p4[(size_t)gi * 16 + q];
    const float* rf = (const float*)r;                     // static-indexed below
    const float na_r = nab[gi];

    float tv[TOPK]; int tp[TOPK];
    #pragma unroll
    for (int s = 0; s < TOPK; ++s) { tv[s] = FLT_MAX; tp[s] = 0; }

    const int c_lo = w * CPW;
    const int c_hi = (c_lo + CPW < BINSZ) ? (c_lo + CPW) : BINSZ;  // last wave: 59
    for (int cj = c_lo; cj < c_hi; ++cj) {
        const int gc = ord[cj];                 // uniform across wave
        const float colv = pb[(size_t)gc * NF + lane];   // coalesced 256B
        const float cna  = nab[gc];
        float acc = 0.f;
        #pragma unroll
        for (int k = 0; k < 64; ++k) {          // readlane -> SGPR operand FMA
            float bc = __uint_as_float(__builtin_amdgcn_readlane(__float_as_uint(colv), k));
            acc += rf[k] * bc;
        }
        float d2 = na_r - 2.f * acc + cna;
        if (d2 < tv[TOPK - 1]) {                // strict <: ties keep earlier pos
            tv[TOPK - 1] = d2; tp[TOPK - 1] = cj;
            #pragma unroll
            for (int s = TOPK - 1; s > 0; --s) {
                if (tv[s] < tv[s - 1]) {
                    float fv = tv[s]; tv[s] = tv[s - 1]; tv[s - 1] = fv;
                    int   fi = tp[s]; tp[s] = tp[s - 1]; tp[s - 1] = fi;
                }
            }
        }
    }

    #pragma unroll
    for (int s = 0; s < TOPK; ++s) { sh_mv[w][lane][s] = tv[s]; sh_mi[w][lane][s] = tp[s]; }
    __syncthreads();

    if (tid < 64) {
        const int r_ = tid;
        const int my = rb * 64 + r_;
        if (my < BINSZ) {
            int h[8] = {0, 0, 0, 0, 0, 0, 0, 0};
            const int src = ord[my];
            float* orow = out + ((size_t)b * NPTS + src) * NPTS;
            #pragma unroll
            for (int s = 0; s < TOPK; ++s) {
                float best = sh_mv[0][r_][h[0]]; int bw = 0;
                #pragma unroll
                for (int ww = 1; ww < 8; ++ww) {
                    float v = sh_mv[ww][r_][h[ww]];
                    if (v < best) { best = v; bw = ww; }   // ties -> lower wave = earlier pos
                }
                const int j = sh_mi[bw][r_][h[bw]];
                h[bw]++;
                float val = expf(-0.1f * sqrtf(fmaxf(best, 1e-6f)));
                orow[ord[j]] = val;
            }
        }
    }
}

// ---------------------------------------------------------------------------
extern "C" void kernel_launch(void* const* d_in, const int* in_sizes, int n_in,
                              void* d_out, int out_size, void* d_ws, size_t ws_size,
                              hipStream_t stream) {
    const float* points = (const float*)d_in[0];
    const float* rot    = (const float*)d_in[1];
    float* out = (float*)d_out;

    char* ws = (char*)d_ws;
    int*   bin_idx = (int*)ws;   ws += NBATCH * NPTS * sizeof(int);
    float* na      = (float*)ws; ws += NBATCH * NPTS * sizeof(float);
    int*   order   = (int*)ws;   // ~120 KB total

    bin_norm_zero_k<<<2500 + NZ, 256, 0, stream>>>(points, rot, bin_idx, na, out);
    sort_k<<<NBATCH, 256, 0, stream>>>(bin_idx, order);
    pair_merge_inject_k<<<NBATCH * NB * 8, 512, 0, stream>>>(points, na, order, out);
}